// Round 7
// baseline (423.995 us; speedup 1.0000x reference)
//
#include <hip/hip_runtime.h>
#include <hip/hip_bf16.h>
#include <cstdint>

typedef __attribute__((ext_vector_type(8))) short short8_t;
typedef __attribute__((ext_vector_type(4))) short s16x4;
typedef __attribute__((ext_vector_type(4))) float f32x4;

#define SEQ 2048
#define BATCH 2
#define DM 2048
#define NH 16
#define HD 128
#define SCALE 0.08838834764831845f  // 1/sqrt(128)

__device__ __forceinline__ short f2bf(float f) {
    union { __hip_bfloat16 h; short s; } u; u.h = __float2bfloat16(f); return u.s;
}
__device__ __forceinline__ float bf2f(short s) {
    union { short s; __hip_bfloat16 h; } u; u.s = s; return __bfloat162float(u.h);
}

#define DSREAD(d, a) asm volatile("ds_read_b128 %0, %1" : "=&v"(d) : "v"(a))

// ---------------- fused prep: weight cast + rope table + L2 norm ----------------
__global__ void __launch_bounds__(256) prep_kernel(const float* __restrict__ qw,
                                                   const float* __restrict__ kw,
                                                   const float* __restrict__ vw,
                                                   const float* __restrict__ ow,
                                                   short* __restrict__ wqkv,
                                                   const float* __restrict__ x,
                                                   const float* __restrict__ nw,
                                                   short* __restrict__ xn,
                                                   float* __restrict__ cosT,
                                                   float* __restrict__ sinT) {
    const int bid = blockIdx.x;
    const int t = threadIdx.x;
    if (bid < 2048) {
        const int per = DM * DM / 4;
        int i = bid * 256 + t;
        const int stride = 2048 * 256;
        for (; i < 4 * per; i += stride) {
            int region = i / per;
            int off = i - region * per;
            const float* src = region == 0 ? qw : (region == 1 ? kw : (region == 2 ? vw : ow));
            float4 v = ((const float4*)src)[off];
            s16x4 o;
            o[0] = f2bf(v.x); o[1] = f2bf(v.y); o[2] = f2bf(v.z); o[3] = f2bf(v.w);
            ((s16x4*)(wqkv + (size_t)region * DM * DM))[off] = o;
        }
    } else if (bid < 2560) {
        int j = (bid - 2048) * 256 + t;
        int tpos = j >> 6, i = j & 63;
        float inv = exp2f(-(2.0f * (float)i / 128.0f) * log2f(10000.0f));
        float a = (float)tpos * inv;
        cosT[tpos * 64 + i] = cosf(a);
        sinT[tpos * 64 + i] = sinf(a);
    } else {
        __shared__ float red[4];
        int row = bid - 2560;
        const float* xr = x + (size_t)row * DM;
        short* outr = xn + (size_t)row * DM;
        float vals[8];
        float ss = 0.f;
#pragma unroll
        for (int i = 0; i < 8; ++i) { float v = xr[t + 256 * i]; vals[i] = v; ss += v * v; }
#pragma unroll
        for (int off = 1; off < 64; off <<= 1) ss += __shfl_xor(ss, off);
        int lane = t & 63, wv = t >> 6;
        if (lane == 0) red[wv] = ss;
        __syncthreads();
        float tot = red[0] + red[1] + red[2] + red[3];
        float inv = 1.f / (sqrtf(tot) + 1e-5f);
#pragma unroll
        for (int i = 0; i < 8; ++i)
            outr[t + 256 * i] = f2bf(vals[i] * inv * nw[t + 256 * i]);
    }
}

// ================= 256x256 8-phase QKV GEMM — asm ds_read pinned =================
// C[m][n] = sum_k A[m][k]*B[n][k]; 512 thr, 8 waves (2Mx4N), BK=64, 2dbuf x 2half,
// XOR chunk swizzle slot^=(row&7) (linear gload_lds dest + inv-perm source + perm read).
__device__ __forceinline__ void stage_half(const short* __restrict__ G, int gRow0, int K, int kOff,
                                           short* ldsBase, int w, int lane) {
#pragma unroll
    for (int j = 0; j < 2; ++j) {
        int c = j * 512 + w * 64 + lane;
        int row = c >> 3;
        int slot = (c & 7) ^ (row & 7);
        const short* g = G + (size_t)(gRow0 + row) * K + kOff + slot * 8;
        __builtin_amdgcn_global_load_lds((const __attribute__((address_space(1))) void*)g,
                                         (__attribute__((address_space(3))) void*)(ldsBase + (j * 512 + w * 64) * 8),
                                         16, 0, 0);
    }
}

__device__ __forceinline__ void q16(f32x4 (&acc)[8][4], short8_t (&aa)[4][2], short8_t (&bb)[4][2],
                                    int ib, int jb) {
#pragma unroll
    for (int ks = 0; ks < 2; ++ks)
#pragma unroll
        for (int ii = 0; ii < 4; ++ii)
#pragma unroll
            for (int jj = 0; jj < 2; ++jj)
                acc[ib + ii][jb + jj] = __builtin_amdgcn_mfma_f32_16x16x32_bf16(
                    aa[ii][ks], bb[jb + jj][ks], acc[ib + ii][jb + jj], 0, 0, 0);
}

template <bool LAST>
__device__ __forceinline__ void kpair(short* lds, uint32_t uA, uint32_t uAx, uint32_t uB, uint32_t uBx,
                                      const short* __restrict__ A, const short* __restrict__ B,
                                      int brow, int bcol, int K, int it,
                                      f32x4 (&acc)[8][4], int w, int lane) {
    const int t1 = 2 * it + 1, p0 = 2 * it + 2, p1 = 2 * it + 3;
    short* ldsA = lds;
    short* ldsB = lds + 32768;
    short8_t af[4][2], bf[4][2], ag[4][2];

    // ---------- P1: read buf0 A[0-3]x2 + B[0-1]x2; stage buf1.A1 <- t1 ----------
#pragma unroll
    for (int i = 0; i < 4; ++i) { DSREAD(af[i][0], uA + i * 2048); DSREAD(af[i][1], uAx + i * 2048); }
#pragma unroll
    for (int j = 0; j < 2; ++j) { DSREAD(bf[j][0], uB + j * 2048); DSREAD(bf[j][1], uBx + j * 2048); }
    stage_half(A, brow + 128, K, t1 * 64, ldsA + 24576, w, lane);
    asm volatile("s_waitcnt lgkmcnt(8)" ::: "memory");
    __builtin_amdgcn_s_barrier();
    asm volatile("s_waitcnt lgkmcnt(0)" ::: "memory");
    __builtin_amdgcn_sched_barrier(0);
    __builtin_amdgcn_s_setprio(1);
    q16(acc, af, bf, 0, 0);
    __builtin_amdgcn_s_setprio(0);
    __builtin_amdgcn_s_barrier();

    // ---------- P2: read buf0 B[2-3]x2 ----------
#pragma unroll
    for (int j = 2; j < 4; ++j) { DSREAD(bf[j][0], uB + j * 2048); DSREAD(bf[j][1], uBx + j * 2048); }
    __builtin_amdgcn_s_barrier();
    asm volatile("s_waitcnt lgkmcnt(0)" ::: "memory");
    __builtin_amdgcn_sched_barrier(0);
    __builtin_amdgcn_s_setprio(1);
    q16(acc, af, bf, 0, 2);
    __builtin_amdgcn_s_setprio(0);
    __builtin_amdgcn_s_barrier();

    // ---------- P3: read buf0 A[4-7]x2; stage buf0.B0 <- p0 ----------
#pragma unroll
    for (int i = 0; i < 4; ++i) { DSREAD(ag[i][0], uA + (i + 4) * 2048); DSREAD(ag[i][1], uAx + (i + 4) * 2048); }
    if (!LAST) stage_half(B, bcol, K, p0 * 64, ldsB, w, lane);
    __builtin_amdgcn_s_barrier();
    asm volatile("s_waitcnt lgkmcnt(0)" ::: "memory");
    __builtin_amdgcn_sched_barrier(0);
    __builtin_amdgcn_s_setprio(1);
    q16(acc, ag, bf, 4, 0);
    __builtin_amdgcn_s_setprio(0);
    __builtin_amdgcn_s_barrier();

    // ---------- P4: stage buf0.B1, buf0.A0 <- p0; vmcnt checkpoint ----------
    if (!LAST) {
        stage_half(B, bcol + 128, K, p0 * 64, ldsB + 8192, w, lane);
        stage_half(A, brow, K, p0 * 64, ldsA, w, lane);
    }
    __builtin_amdgcn_s_barrier();
    __builtin_amdgcn_s_setprio(1);
    q16(acc, ag, bf, 4, 2);
    __builtin_amdgcn_s_setprio(0);
    if (!LAST) asm volatile("s_waitcnt vmcnt(6)" ::: "memory");
    else       asm volatile("s_waitcnt vmcnt(0)" ::: "memory");
    __builtin_amdgcn_s_barrier();

    // ---------- P5: read buf1 A[0-3]+B[0-1]; stage buf0.A1 <- p0 ----------
#pragma unroll
    for (int i = 0; i < 4; ++i) { DSREAD(af[i][0], uA + 32768 + i * 2048); DSREAD(af[i][1], uAx + 32768 + i * 2048); }
#pragma unroll
    for (int j = 0; j < 2; ++j) { DSREAD(bf[j][0], uB + 32768 + j * 2048); DSREAD(bf[j][1], uBx + 32768 + j * 2048); }
    if (!LAST) stage_half(A, brow + 128, K, p0 * 64, ldsA + 8192, w, lane);
    asm volatile("s_waitcnt lgkmcnt(8)" ::: "memory");
    __builtin_amdgcn_s_barrier();
    asm volatile("s_waitcnt lgkmcnt(0)" ::: "memory");
    __builtin_amdgcn_sched_barrier(0);
    __builtin_amdgcn_s_setprio(1);
    q16(acc, af, bf, 0, 0);
    __builtin_amdgcn_s_setprio(0);
    __builtin_amdgcn_s_barrier();

    // ---------- P6: read buf1 B[2-3] ----------
#pragma unroll
    for (int j = 2; j < 4; ++j) { DSREAD(bf[j][0], uB + 32768 + j * 2048); DSREAD(bf[j][1], uBx + 32768 + j * 2048); }
    __builtin_amdgcn_s_barrier();
    asm volatile("s_waitcnt lgkmcnt(0)" ::: "memory");
    __builtin_amdgcn_sched_barrier(0);
    __builtin_amdgcn_s_setprio(1);
    q16(acc, af, bf, 0, 2);
    __builtin_amdgcn_s_setprio(0);
    __builtin_amdgcn_s_barrier();

    // ---------- P7: read buf1 A[4-7]; stage buf1.B0 <- p1 ----------
#pragma unroll
    for (int i = 0; i < 4; ++i) { DSREAD(ag[i][0], uA + 32768 + (i + 4) * 2048); DSREAD(ag[i][1], uAx + 32768 + (i + 4) * 2048); }
    if (!LAST) stage_half(B, bcol, K, p1 * 64, ldsB + 16384, w, lane);
    __builtin_amdgcn_s_barrier();
    asm volatile("s_waitcnt lgkmcnt(0)" ::: "memory");
    __builtin_amdgcn_sched_barrier(0);
    __builtin_amdgcn_s_setprio(1);
    q16(acc, ag, bf, 4, 0);
    __builtin_amdgcn_s_setprio(0);
    __builtin_amdgcn_s_barrier();

    // ---------- P8: stage buf1.B1, buf1.A0 <- p1; vmcnt checkpoint ----------
    if (!LAST) {
        stage_half(B, bcol + 128, K, p1 * 64, ldsB + 24576, w, lane);
        stage_half(A, brow, K, p1 * 64, ldsA + 16384, w, lane);
    }
    __builtin_amdgcn_s_barrier();
    __builtin_amdgcn_s_setprio(1);
    q16(acc, ag, bf, 4, 2);
    __builtin_amdgcn_s_setprio(0);
    if (!LAST) asm volatile("s_waitcnt vmcnt(6)" ::: "memory");
    __builtin_amdgcn_s_barrier();
}

__global__ void __launch_bounds__(512, 2) gemm8p(const short* __restrict__ A,
                                                 const short* __restrict__ B,
                                                 int Mt, int Nt, int K,
                                                 short* __restrict__ oq, short* __restrict__ ok,
                                                 short* __restrict__ ov,
                                                 const float* __restrict__ bq,
                                                 const float* __restrict__ bk,
                                                 const float* __restrict__ bv) {
    extern __shared__ short lds[];   // 65536 shorts = 128 KiB
    const int tid = threadIdx.x;
    const int lane = tid & 63;
    const int w = tid >> 6;
    const int wr = w >> 2;
    const int wc = w & 3;

    const int nwg = Mt * Nt;                 // % 8 == 0
    const int cpx = nwg >> 3;
    const int bid = blockIdx.x;
    const int swz = (bid & 7) * cpx + (bid >> 3);
    const int brow = (swz % Mt) * 256;
    const int bcol = (swz / Mt) * 256;

    f32x4 acc[8][4];
#pragma unroll
    for (int i = 0; i < 8; ++i)
#pragma unroll
        for (int j = 0; j < 4; ++j) acc[i][j] = (f32x4){0.f, 0.f, 0.f, 0.f};

    short* ldsA = lds;
    short* ldsB = lds + 32768;

    const int fr = lane & 15;
    const int fs = lane >> 4;
    const int c0 = fs ^ (fr & 7);
    const uint32_t ldsBase = (uint32_t)(uintptr_t)&lds[0];
    const uint32_t uA  = ldsBase + (uint32_t)(wr * 16384 + fr * 128 + c0 * 16);
    const uint32_t uAx = ldsBase + (uint32_t)(wr * 16384 + fr * 128 + (c0 ^ 4) * 16);
    const uint32_t uB  = ldsBase + 65536u + (uint32_t)((wc >> 1) * 16384 + (wc & 1) * 8192 + fr * 128 + c0 * 16);
    const uint32_t uBx = ldsBase + 65536u + (uint32_t)((wc >> 1) * 16384 + (wc & 1) * 8192 + fr * 128 + (c0 ^ 4) * 16);

    // prologue: buf0 <- tile0 {B0,B1,A0,A1}; buf1 <- tile1 {B0,B1,A0}
    stage_half(B, bcol,       K, 0,  ldsB,          w, lane);
    stage_half(B, bcol + 128, K, 0,  ldsB + 8192,   w, lane);
    stage_half(A, brow,       K, 0,  ldsA,          w, lane);
    stage_half(A, brow + 128, K, 0,  ldsA + 8192,   w, lane);
    stage_half(B, bcol,       K, 64, ldsB + 16384,  w, lane);
    stage_half(B, bcol + 128, K, 64, ldsB + 24576,  w, lane);
    stage_half(A, brow,       K, 64, ldsA + 16384,  w, lane);
    asm volatile("s_waitcnt vmcnt(6)" ::: "memory");
    __builtin_amdgcn_s_barrier();

    const int niter = K / 128;
    for (int it = 0; it < niter - 1; ++it)
        kpair<false>(lds, uA, uAx, uB, uBx, A, B, brow, bcol, K, it, acc, w, lane);
    kpair<true>(lds, uA, uAx, uB, uBx, A, B, brow, bcol, K, niter - 1, acc, w, lane);

    // epilogue: QKV scatter. C frag: col = lane&15 (n), row = (lane>>4)*4 + jj (m)
    const int fq = (lane >> 4) * 4;
#pragma unroll
    for (int i = 0; i < 8; ++i) {
        int mrow = brow + wr * 128 + i * 16 + fq;
#pragma unroll
        for (int j = 0; j < 4; ++j) {
            int ncol = bcol + wc * 64 + j * 16 + fr;
            int which = ncol >> 11;
            int hl = ncol & 2047;
            int h = hl >> 7, d = hl & 127;
            const float* bp = which == 0 ? bq : (which == 1 ? bk : bv);
            short* dst = which == 0 ? oq : (which == 1 ? ok : ov);
            float bval = bp[hl];
#pragma unroll
            for (int jj = 0; jj < 4; ++jj) {
                int m = mrow + jj;
                int s = m >> 1, b = m & 1;
                float v = acc[i][j][jj] + bval;
                size_t idx;
                if (which == 2)
                    idx = (((size_t)(b * NH + h)) * HD + d) * SEQ + s;   // V transposed (b,h,d,s)
                else
                    idx = (((size_t)(b * NH + h)) * SEQ + s) * HD + d;   // (b,h,s,d)
                dst[idx] = f2bf(v);
            }
        }
    }
}

// ========== 128x128 BK=64 GEMM, double-buffered, counted vmcnt, asm ds_read ==========
template <int MODE>
__global__ void __launch_bounds__(256) gemm_db(const short* __restrict__ A,
                                               const short* __restrict__ B,
                                               int N, int K,
                                               float* __restrict__ outF,
                                               const float* __restrict__ bias) {
    extern __shared__ short lds[];
    const int tid = threadIdx.x;
    const int lane = tid & 63;
    const int w = tid >> 6;
    const int wr = w >> 1, wc = w & 1;
    const int brow = blockIdx.y * 128;
    const int bcol = blockIdx.x * 128;

    const short* gA[4]; const short* gB[4]; int ldsC[4];
#pragma unroll
    for (int p = 0; p < 4; ++p) {
        int c = p * 256 + tid;
        int row = c >> 3;
        int slot = (c & 7) ^ (row & 7);
        gA[p] = A + (size_t)(brow + row) * K + slot * 8;
        gB[p] = B + (size_t)(bcol + row) * K + slot * 8;
        ldsC[p] = c * 8;
    }
    const uint32_t ldsBase = (uint32_t)(uintptr_t)&lds[0];

    f32x4 acc[4][4];
#pragma unroll
    for (int i = 0; i < 4; ++i)
#pragma unroll
        for (int j = 0; j < 4; ++j) acc[i][j] = (f32x4){0.f, 0.f, 0.f, 0.f};

    const int fr = lane & 15;
    const int fs = lane >> 4;
    uint32_t aOff[4][2], bOff[4][2];
#pragma unroll
    for (int i = 0; i < 4; ++i)
#pragma unroll
        for (int ks = 0; ks < 2; ++ks) {
            int ch = (ks * 4 + fs) ^ (fr & 7);
            int ar = wr * 64 + i * 16 + fr;
            int br = wc * 64 + i * 16 + fr;
            aOff[i][ks] = ldsBase + (uint32_t)(ar * 128 + ch * 16);
            bOff[i][ks] = ldsBase + 32768u + (uint32_t)(br * 128 + ch * 16);
        }

    const int nt = K >> 6;
#pragma unroll
    for (int p = 0; p < 4; ++p)
        __builtin_amdgcn_global_load_lds((const __attribute__((address_space(1))) void*)gA[p],
                                         (__attribute__((address_space(3))) void*)(lds + ldsC[p]), 16, 0, 0);
#pragma unroll
    for (int p = 0; p < 4; ++p)
        __builtin_amdgcn_global_load_lds((const __attribute__((address_space(1))) void*)gB[p],
                                         (__attribute__((address_space(3))) void*)(lds + 16384 + ldsC[p]), 16, 0, 0);

    for (int t = 0; t < nt; ++t) {
        const int cur = t & 1;
        if (t + 1 < nt) {
            const int nb = (t + 1) & 1;
            const int kb = (t + 1) << 6;
#pragma unroll
            for (int p = 0; p < 4; ++p)
                __builtin_amdgcn_global_load_lds((const __attribute__((address_space(1))) void*)(gA[p] + kb),
                                                 (__attribute__((address_space(3))) void*)(lds + nb * 8192 + ldsC[p]), 16, 0, 0);
#pragma unroll
            for (int p = 0; p < 4; ++p)
                __builtin_amdgcn_global_load_lds((const __attribute__((address_space(1))) void*)(gB[p] + kb),
                                                 (__attribute__((address_space(3))) void*)(lds + 16384 + nb * 8192 + ldsC[p]), 16, 0, 0);
            asm volatile("s_waitcnt vmcnt(8)" ::: "memory");
        } else {
            asm volatile("s_waitcnt vmcnt(0)" ::: "memory");
        }
        __builtin_amdgcn_s_barrier();

        const uint32_t ab = (uint32_t)(cur * 16384);
        short8_t af[4][2], bfv[4][2];
#pragma unroll
        for (int i = 0; i < 4; ++i)
#pragma unroll
            for (int ks = 0; ks < 2; ++ks) DSREAD(af[i][ks], aOff[i][ks] + ab);
#pragma unroll
        for (int j = 0; j < 4; ++j)
#pragma unroll
            for (int ks = 0; ks < 2; ++ks) DSREAD(bfv[j][ks], bOff[j][ks] + ab);
        asm volatile("s_waitcnt lgkmcnt(0)" ::: "memory");
        __builtin_amdgcn_sched_barrier(0);

        __builtin_amdgcn_s_setprio(1);
#pragma unroll
        for (int ks = 0; ks < 2; ++ks)
#pragma unroll
            for (int i = 0; i < 4; ++i)
#pragma unroll
                for (int j = 0; j < 4; ++j)
                    acc[i][j] = __builtin_amdgcn_mfma_f32_16x16x32_bf16(af[i][ks], bfv[j][ks], acc[i][j], 0, 0, 0);
        __builtin_amdgcn_s_setprio(0);
        __builtin_amdgcn_s_barrier();
    }

    const int fq = (lane >> 4) * 4;
#pragma unroll
    for (int i = 0; i < 4; ++i) {
        int mrow = brow + wr * 64 + i * 16 + fq;
#pragma unroll
        for (int j = 0; j < 4; ++j) {
            int ncol = bcol + wc * 64 + j * 16 + fr;
            float bval = bias[ncol];
#pragma unroll
            for (int jj = 0; jj < 4; ++jj) {
                int m = mrow + jj;
                outF[(size_t)m * N + ncol] = acc[i][j][jj] + bval;
            }
        }
    }
}

// ---------------- RoPE in-place on k only (b,h,s,d) bf16 ----------------
__global__ void __launch_bounds__(256) rope_k_kernel(short* __restrict__ k,
                                                     const float* __restrict__ cosT,
                                                     const float* __restrict__ sinT) {
    int w = threadIdx.x >> 6, lane = threadIdx.x & 63;
    int idx = blockIdx.x * 4 + w;
    int s = idx & (SEQ - 1);
    size_t base = (size_t)idx * HD;
    float c = cosT[s * 64 + lane], sn = sinT[s * 64 + lane];
    float k1 = bf2f(k[base + lane]), k2 = bf2f(k[base + lane + 64]);
    k[base + lane] = f2bf(k1 * c - k2 * sn);
    k[base + lane + 64] = f2bf(k2 * c + k1 * sn);
}

// ---------------- Flash attention (causal), 8 waves x 16 q-rows (QBLK=128), KV tile 64 ----
__global__ void __launch_bounds__(512) attn_kernel(const short* __restrict__ Q,
                                                   const short* __restrict__ K,
                                                   const short* __restrict__ V,
                                                   const float* __restrict__ cosT,
                                                   const float* __restrict__ sinT,
                                                   short* __restrict__ AO) {
    __shared__ short Kl[64 * 136];
    __shared__ short Vt[128 * 88];
    __shared__ short Pl[8][16 * 88];

    const int bh = blockIdx.x;
    const int qt = blockIdx.y;
    const int b = bh >> 4;
    const int h = bh & 15;
    const size_t base = (size_t)bh * (SEQ * HD);
    const int tid = threadIdx.x;
    const int lane = tid & 63;
    const int w = tid >> 6;
    const int fr = lane & 15;
    const int fk = (lane >> 4) * 8;
    const int fq = (lane >> 4) * 4;
    const int qbase = qt * 128 + w * 16;
    const int qg = qbase + fr;

    const int kr = tid >> 4;
    const int kc8 = (tid & 15) * 8;
    const int vd = tid >> 3;
    const int vc8 = (tid & 7) * 8;

    short8_t qf[4];
#pragma unroll
    for (int kc = 0; kc < 4; ++kc)
        qf[kc] = *(const short8_t*)&Q[base + (size_t)(qg) * HD + kc * 32 + fk];

    {
        const float* cb = cosT + (size_t)qg * 64;
        const float* sb = sinT + (size_t)qg * 64;
#pragma unroll
        for (int kc = 0; kc < 2; ++kc) {
            float4 c0 = *(const float4*)&cb[kc * 32 + fk];
            float4 c1 = *(const float4*)&cb[kc * 32 + fk + 4];
            float4 s0 = *(const float4*)&sb[kc * 32 + fk];
            float4 s1 = *(const float4*)&sb[kc * 32 + fk + 4];
            float cv[8] = {c0.x, c0.y, c0.z, c0.w, c1.x, c1.y, c1.z, c1.w};
            float sv[8] = {s0.x, s0.y, s0.z, s0.w, s1.x, s1.y, s1.z, s1.w};
#pragma unroll
            for (int e = 0; e < 8; ++e) {
                float q1 = bf2f(qf[kc][e]), q2 = bf2f(qf[kc + 2][e]);
                qf[kc][e]     = f2bf((q1 * cv[e] - q2 * sv[e]) * SCALE);
                qf[kc + 2][e] = f2bf((q2 * cv[e] + q1 * sv[e]) * SCALE);
            }
        }
    }

    f32x4 acc[8];
#pragma unroll
    for (int dt = 0; dt < 8; ++dt) acc[dt] = (f32x4){0.f, 0.f, 0.f, 0.f};
    float m_r = -1e30f, l_r = 0.f;

    const int ktmax = qt * 2 + 1;

    short8_t kreg[2], vreg[2];
#pragma unroll
    for (int p = 0; p < 2; ++p) {
        kreg[p] = *(const short8_t*)&K[base + (size_t)(p * 32 + kr) * HD + kc8];
        vreg[p] = *(const short8_t*)&V[base + (size_t)(p * 64 + vd) * SEQ + vc8];
    }
#pragma unroll
    for (int p = 0; p < 2; ++p) {
        *(short8_t*)&Kl[(p * 32 + kr) * 136 + kc8] = kreg[p];
        *(short8_t*)&Vt[(p * 64 + vd) * 88 + vc8] = vreg[p];
    }
    __syncthreads();

    for (int kt = 0; kt <= ktmax; ++kt) {
        const bool active = (kt * 64 <= qbase + 15);
        f32x4 st[4];
        if (active) {
            __builtin_amdgcn_s_setprio(1);
#pragma unroll
            for (int nt = 0; nt < 4; ++nt) {
                f32x4 a = (f32x4){0.f, 0.f, 0.f, 0.f};
#pragma unroll
                for (int kc = 0; kc < 4; ++kc) {
                    short8_t kf = *(const short8_t*)&Kl[(nt * 16 + fr) * 136 + kc * 32 + fk];
                    a = __builtin_amdgcn_mfma_f32_16x16x32_bf16(kf, qf[kc], a, 0, 0, 0);
                }
                st[nt] = a;
            }
            __builtin_amdgcn_s_setprio(0);
        }

        if (kt < ktmax) {
            const size_t kb2 = base + (size_t)((kt + 1) * 64) * HD;
            const size_t vb2 = base + (size_t)(kt + 1) * 64;
#pragma unroll
            for (int p = 0; p < 2; ++p) {
                kreg[p] = *(const short8_t*)&K[kb2 + (size_t)(p * 32 + kr) * HD + kc8];
                vreg[p] = *(const short8_t*)&V[vb2 + (size_t)(p * 64 + vd) * SEQ + vc8];
            }
        }

        if (active) {
            const bool needMask = (kt * 64 + 63 > qbase);
            float rmax = -1e30f;
            if (needMask) {
#pragma unroll
                for (int nt = 0; nt < 4; ++nt)
#pragma unroll
                    for (int jj = 0; jj < 4; ++jj) {
                        int kg = kt * 64 + nt * 16 + fq + jj;
                        float sv = st[nt][jj];
                        sv = (kg > qg) ? -1e30f : sv;
                        st[nt][jj] = sv;
                        rmax = fmaxf(rmax, sv);
                    }
            } else {
#pragma unroll
                for (int nt = 0; nt < 4; ++nt)
#pragma unroll
                    for (int jj = 0; jj < 4; ++jj) rmax = fmaxf(rmax, st[nt][jj]);
            }
            rmax = fmaxf(rmax, __shfl_xor(rmax, 16));
            rmax = fmaxf(rmax, __shfl_xor(rmax, 32));

            const bool doRescale = !(m_r > -1e29f && __all(rmax - m_r <= 8.0f));
            float m_new = doRescale ? fmaxf(m_r, rmax) : m_r;
            float rsum = 0.f;
#pragma unroll
            for (int nt = 0; nt < 4; ++nt) {
                s16x4 pk;
#pragma unroll
                for (int jj = 0; jj < 4; ++jj) {
                    float p = __expf(st[nt][jj] - m_new);
                    rsum += p;
                    pk[jj] = f2bf(p);
                }
                *(s16x4*)&Pl[w][fr * 88 + nt * 16 + fq] = pk;
            }
            rsum += __shfl_xor(rsum, 16);
            rsum += __shfl_xor(rsum, 32);
            if (doRescale) {
                float corr = __expf(m_r - m_new);
                l_r = l_r * corr + rsum;
                m_r = m_new;
                float c4[4];
#pragma unroll
                for (int jj = 0; jj < 4; ++jj) c4[jj] = __shfl(corr, fq + jj);
#pragma unroll
                for (int dt = 0; dt < 8; ++dt)
#pragma unroll
                    for (int jj = 0; jj < 4; ++jj) acc[dt][jj] *= c4[jj];
            } else {
                l_r += rsum;
            }

            __builtin_amdgcn_s_setprio(1);
#pragma unroll
            for (int kc = 0; kc < 2; ++kc) {
                short8_t pf = *(const short8_t*)&Pl[w][fr * 88 + kc * 32 + fk];
#pragma unroll
                for (int dt = 0; dt < 8; ++dt) {
                    short8_t vf = *(const short8_t*)&Vt[(dt * 16 + fr) * 88 + kc * 32 + fk];
                    acc[dt] = __builtin_amdgcn_mfma_f32_16x16x32_bf16(pf, vf, acc[dt], 0, 0, 0);
                }
            }
            __builtin_amdgcn_s_setprio(0);
        }

        __syncthreads();
        if (kt < ktmax) {
#pragma unroll
            for (int p = 0; p < 2; ++p) {
                *(short8_t*)&Kl[(p * 32 + kr) * 136 + kc8] = kreg[p];
                *(short8_t*)&Vt[(p * 64 + vd) * 88 + vc8] = vreg[p];
            }
            __syncthreads();
        }
    }

    float linv[4];
#pragma unroll
    for (int jj = 0; jj < 4; ++jj) linv[jj] = 1.f / __shfl(l_r, fq + jj);
#pragma unroll
    for (int dt = 0; dt < 8; ++dt) {
#pragma unroll
        for (int jj = 0; jj < 4; ++jj) {
            int qrow = qbase + fq + jj;
            int d = dt * 16 + fr;
            AO[((size_t)(qrow * BATCH + b)) * DM + h * HD + d] = f2bf(acc[dt][jj] * linv[jj]);
        }
    }
}

extern "C" void kernel_launch(void* const* d_in, const int* in_sizes, int n_in,
                              void* d_out, int out_size, void* d_ws, size_t ws_size,
                              hipStream_t stream) {
    (void)in_sizes; (void)n_in; (void)out_size; (void)ws_size;
    const float* x  = (const float*)d_in[0];
    const float* nw = (const float*)d_in[3];
    const float* qw = (const float*)d_in[4];
    const float* qbias = (const float*)d_in[5];
    const float* kw = (const float*)d_in[6];
    const float* kbias = (const float*)d_in[7];
    const float* vw = (const float*)d_in[8];
    const float* vbias = (const float*)d_in[9];
    const float* ow = (const float*)d_in[10];
    const float* obias = (const float*)d_in[11];
    float* out = (float*)d_out;

    char* ws = (char*)d_ws;
    size_t off = 0;
    float* cosT = (float*)(ws + off); off += (size_t)SEQ * 64 * 4;
    float* sinT = (float*)(ws + off); off += (size_t)SEQ * 64 * 4;
    short* wqkv = (short*)(ws + off); off += (size_t)3 * DM * DM * 2;
    short* wo   = (short*)(ws + off); off += (size_t)DM * DM * 2;
    short* xn   = (short*)(ws + off); off += (size_t)SEQ * BATCH * DM * 2;  // reused as AO
    short* qd   = (short*)(ws + off); off += (size_t)SEQ * BATCH * DM * 2;
    short* kd   = (short*)(ws + off); off += (size_t)SEQ * BATCH * DM * 2;
    short* vd   = (short*)(ws + off); off += (size_t)SEQ * BATCH * DM * 2;
    short* ao   = xn;

    hipFuncSetAttribute((const void*)gemm8p, hipFuncAttributeMaxDynamicSharedMemorySize, 131072);
    hipFuncSetAttribute((const void*)gemm_db<1>, hipFuncAttributeMaxDynamicSharedMemorySize, 65536);

    prep_kernel<<<2560 + SEQ * BATCH, 256, 0, stream>>>(qw, kw, vw, ow, wqkv, x, nw, xn, cosT, sinT);
    gemm8p<<<dim3(16 * 24), 512, 131072, stream>>>(
        xn, wqkv, 16, 24, DM, qd, kd, vd, qbias, kbias, vbias);
    rope_k_kernel<<<BATCH * NH * SEQ / 4, 256, 0, stream>>>(kd, cosT, sinT);
    attn_kernel<<<dim3(BATCH * NH, SEQ / 128), 512, 0, stream>>>(qd, kd, vd, cosT, sinT, ao);
    gemm_db<1><<<dim3(DM / 128, SEQ * BATCH / 128), 256, 65536, stream>>>(
        ao, wo, DM, DM, out, obias);
}

// Round 8
// 280.637 us; speedup vs baseline: 1.5108x; 1.5108x over previous
//
#include <hip/hip_runtime.h>
#include <hip/hip_bf16.h>
#include <cstdint>

typedef __attribute__((ext_vector_type(8))) short short8_t;
typedef __attribute__((ext_vector_type(4))) short s16x4;
typedef __attribute__((ext_vector_type(4))) float f32x4;

#define SEQ 2048
#define BATCH 2
#define DM 2048
#define NH 16
#define HD 128
#define SCALE_LOG2E 0.1275174400948802f   // (1/sqrt(128)) * log2(e)

__device__ __forceinline__ short f2bf(float f) {
    union { __hip_bfloat16 h; short s; } u; u.h = __float2bfloat16(f); return u.s;
}
__device__ __forceinline__ float bf2f(short s) {
    union { short s; __hip_bfloat16 h; } u; u.s = s; return __bfloat162float(u.h);
}

#define DSREAD(d, a) asm volatile("ds_read_b128 %0, %1" : "=&v"(d) : "v"(a))

// ---------------- fused prep: weight cast + rope table + L2 norm ----------------
__global__ void __launch_bounds__(256) prep_kernel(const float* __restrict__ qw,
                                                   const float* __restrict__ kw,
                                                   const float* __restrict__ vw,
                                                   const float* __restrict__ ow,
                                                   short* __restrict__ wqkv,
                                                   const float* __restrict__ x,
                                                   const float* __restrict__ nw,
                                                   short* __restrict__ xn,
                                                   float* __restrict__ cosT,
                                                   float* __restrict__ sinT) {
    const int bid = blockIdx.x;
    const int t = threadIdx.x;
    if (bid < 2048) {
        const int per = DM * DM / 4;
        int i = bid * 256 + t;
        const int stride = 2048 * 256;
        for (; i < 4 * per; i += stride) {
            int region = i / per;
            int off = i - region * per;
            const float* src = region == 0 ? qw : (region == 1 ? kw : (region == 2 ? vw : ow));
            float4 v = ((const float4*)src)[off];
            s16x4 o;
            o[0] = f2bf(v.x); o[1] = f2bf(v.y); o[2] = f2bf(v.z); o[3] = f2bf(v.w);
            ((s16x4*)(wqkv + (size_t)region * DM * DM))[off] = o;
        }
    } else if (bid < 2560) {
        int j = (bid - 2048) * 256 + t;
        int tpos = j >> 6, i = j & 63;
        float inv = exp2f(-(2.0f * (float)i / 128.0f) * log2f(10000.0f));
        float a = (float)tpos * inv;
        cosT[tpos * 64 + i] = cosf(a);
        sinT[tpos * 64 + i] = sinf(a);
    } else {
        __shared__ float red[4];
        int row = bid - 2560;
        const float* xr = x + (size_t)row * DM;
        short* outr = xn + (size_t)row * DM;
        float vals[8];
        float ss = 0.f;
#pragma unroll
        for (int i = 0; i < 8; ++i) { float v = xr[t + 256 * i]; vals[i] = v; ss += v * v; }
#pragma unroll
        for (int off = 1; off < 64; off <<= 1) ss += __shfl_xor(ss, off);
        int lane = t & 63, wv = t >> 6;
        if (lane == 0) red[wv] = ss;
        __syncthreads();
        float tot = red[0] + red[1] + red[2] + red[3];
        float inv = 1.f / (sqrtf(tot) + 1e-5f);
#pragma unroll
        for (int i = 0; i < 8; ++i)
            outr[t + 256 * i] = f2bf(vals[i] * inv * nw[t + 256 * i]);
    }
}

// ========== 128x128 BK=64 GEMM, double-buffered, counted vmcnt, asm ds_read ==========
// LDS layout (shorts): A0 @0, A1 @8192, B0 @16384, B1 @24576  (64 KiB total)
template <int MODE>
__global__ void __launch_bounds__(256) gemm_db(const short* __restrict__ A,
                                               const short* __restrict__ B,
                                               int N, int K,
                                               short* __restrict__ oq, short* __restrict__ ok,
                                               short* __restrict__ ov,
                                               const float* __restrict__ bq,
                                               const float* __restrict__ bk,
                                               const float* __restrict__ bv,
                                               float* __restrict__ outF,
                                               const float* __restrict__ bias) {
    extern __shared__ short lds[];
    const int tid = threadIdx.x;
    const int lane = tid & 63;
    const int w = tid >> 6;
    const int wr = w >> 1, wc = w & 1;
    const int brow = blockIdx.y * 128;
    const int bcol = blockIdx.x * 128;

    const short* gA[4]; const short* gB[4]; int ldsC[4];
#pragma unroll
    for (int p = 0; p < 4; ++p) {
        int c = p * 256 + tid;
        int row = c >> 3;
        int slot = (c & 7) ^ (row & 7);
        gA[p] = A + (size_t)(brow + row) * K + slot * 8;
        gB[p] = B + (size_t)(bcol + row) * K + slot * 8;
        ldsC[p] = c * 8;
    }
    const uint32_t ldsBase = (uint32_t)(uintptr_t)&lds[0];

    f32x4 acc[4][4];
#pragma unroll
    for (int i = 0; i < 4; ++i)
#pragma unroll
        for (int j = 0; j < 4; ++j) acc[i][j] = (f32x4){0.f, 0.f, 0.f, 0.f};

    const int fr = lane & 15;
    const int fs = lane >> 4;
    uint32_t aOff[4][2], bOff[4][2];
#pragma unroll
    for (int i = 0; i < 4; ++i)
#pragma unroll
        for (int ks = 0; ks < 2; ++ks) {
            int ch = (ks * 4 + fs) ^ (fr & 7);
            int ar = wr * 64 + i * 16 + fr;
            int br = wc * 64 + i * 16 + fr;
            aOff[i][ks] = ldsBase + (uint32_t)(ar * 128 + ch * 16);
            bOff[i][ks] = ldsBase + 32768u + (uint32_t)(br * 128 + ch * 16);
        }

    const int nt = K >> 6;
#pragma unroll
    for (int p = 0; p < 4; ++p)
        __builtin_amdgcn_global_load_lds((const __attribute__((address_space(1))) void*)gA[p],
                                         (__attribute__((address_space(3))) void*)(lds + ldsC[p]), 16, 0, 0);
#pragma unroll
    for (int p = 0; p < 4; ++p)
        __builtin_amdgcn_global_load_lds((const __attribute__((address_space(1))) void*)gB[p],
                                         (__attribute__((address_space(3))) void*)(lds + 16384 + ldsC[p]), 16, 0, 0);

    for (int t = 0; t < nt; ++t) {
        const int cur = t & 1;
        if (t + 1 < nt) {
            const int nb = (t + 1) & 1;
            const int kb = (t + 1) << 6;
#pragma unroll
            for (int p = 0; p < 4; ++p)
                __builtin_amdgcn_global_load_lds((const __attribute__((address_space(1))) void*)(gA[p] + kb),
                                                 (__attribute__((address_space(3))) void*)(lds + nb * 8192 + ldsC[p]), 16, 0, 0);
#pragma unroll
            for (int p = 0; p < 4; ++p)
                __builtin_amdgcn_global_load_lds((const __attribute__((address_space(1))) void*)(gB[p] + kb),
                                                 (__attribute__((address_space(3))) void*)(lds + 16384 + nb * 8192 + ldsC[p]), 16, 0, 0);
            asm volatile("s_waitcnt vmcnt(8)" ::: "memory");
        } else {
            asm volatile("s_waitcnt vmcnt(0)" ::: "memory");
        }
        __builtin_amdgcn_s_barrier();

        const uint32_t ab = (uint32_t)(cur * 16384);
        short8_t af[4][2], bfv[4][2];
#pragma unroll
        for (int i = 0; i < 4; ++i)
#pragma unroll
            for (int ks = 0; ks < 2; ++ks) DSREAD(af[i][ks], aOff[i][ks] + ab);
#pragma unroll
        for (int j = 0; j < 4; ++j)
#pragma unroll
            for (int ks = 0; ks < 2; ++ks) DSREAD(bfv[j][ks], bOff[j][ks] + ab);
        asm volatile("s_waitcnt lgkmcnt(0)" ::: "memory");
        __builtin_amdgcn_sched_barrier(0);

        __builtin_amdgcn_s_setprio(1);
#pragma unroll
        for (int ks = 0; ks < 2; ++ks)
#pragma unroll
            for (int i = 0; i < 4; ++i)
#pragma unroll
                for (int j = 0; j < 4; ++j)
                    acc[i][j] = __builtin_amdgcn_mfma_f32_16x16x32_bf16(af[i][ks], bfv[j][ks], acc[i][j], 0, 0, 0);
        __builtin_amdgcn_s_setprio(0);
        __builtin_amdgcn_s_barrier();
    }

    const int fq = (lane >> 4) * 4;
#pragma unroll
    for (int i = 0; i < 4; ++i) {
        int mrow = brow + wr * 64 + i * 16 + fq;
#pragma unroll
        for (int j = 0; j < 4; ++j) {
            int ncol = bcol + wc * 64 + j * 16 + fr;
            if (MODE == 0) {
                int which = ncol >> 11;
                int hl = ncol & 2047;
                int h = hl >> 7, d = hl & 127;
                const float* bp = which == 0 ? bq : (which == 1 ? bk : bv);
                short* dst = which == 0 ? oq : (which == 1 ? ok : ov);
                float bval = bp[hl];
#pragma unroll
                for (int jj = 0; jj < 4; ++jj) {
                    int m = mrow + jj;
                    int s = m >> 1, b = m & 1;
                    float v = acc[i][j][jj] + bval;
                    size_t idx;
                    if (which == 2)
                        idx = (((size_t)(b * NH + h)) * HD + d) * SEQ + s;   // V transposed (b,h,d,s)
                    else
                        idx = (((size_t)(b * NH + h)) * SEQ + s) * HD + d;   // (b,h,s,d)
                    dst[idx] = f2bf(v);
                }
            } else {
                float bval = bias[ncol];
#pragma unroll
                for (int jj = 0; jj < 4; ++jj) {
                    int m = mrow + jj;
                    outF[(size_t)m * N + ncol] = acc[i][j][jj] + bval;
                }
            }
        }
    }
}

// ---------------- RoPE in-place on k only (b,h,s,d) bf16 ----------------
__global__ void __launch_bounds__(256) rope_k_kernel(short* __restrict__ k,
                                                     const float* __restrict__ cosT,
                                                     const float* __restrict__ sinT) {
    int w = threadIdx.x >> 6, lane = threadIdx.x & 63;
    int idx = blockIdx.x * 4 + w;
    int s = idx & (SEQ - 1);
    size_t base = (size_t)idx * HD;
    float c = cosT[s * 64 + lane], sn = sinT[s * 64 + lane];
    float k1 = bf2f(k[base + lane]), k2 = bf2f(k[base + lane + 64]);
    k[base + lane] = f2bf(k1 * c - k2 * sn);
    k[base + lane + 64] = f2bf(k2 * c + k1 * sn);
}

// ---------------- Flash attention (causal), 8 waves x 16 q-rows (QBLK=128), KV tile 64 ----
// Grid: (qt, bh) so consecutive blocks share one head's K/V (L2 locality).
// Q scaled by SCALE*log2(e); softmax in exp2 domain. Async-STAGE split; defer-max.
__global__ void __launch_bounds__(512) attn_kernel(const short* __restrict__ Q,
                                                   const short* __restrict__ K,
                                                   const short* __restrict__ V,
                                                   const float* __restrict__ cosT,
                                                   const float* __restrict__ sinT,
                                                   short* __restrict__ AO) {
    __shared__ short Kl[64 * 136];
    __shared__ short Vt[128 * 88];
    __shared__ short Pl[8][16 * 88];

    const int qt = blockIdx.x;
    const int bh = blockIdx.y;
    const int b = bh >> 4;
    const int h = bh & 15;
    const size_t base = (size_t)bh * (SEQ * HD);
    const int tid = threadIdx.x;
    const int lane = tid & 63;
    const int w = tid >> 6;
    const int fr = lane & 15;
    const int fk = (lane >> 4) * 8;
    const int fq = (lane >> 4) * 4;
    const int qbase = qt * 128 + w * 16;
    const int qg = qbase + fr;

    const int kr = tid >> 4;
    const int kc8 = (tid & 15) * 8;
    const int vd = tid >> 3;
    const int vc8 = (tid & 7) * 8;

    short8_t qf[4];
#pragma unroll
    for (int kc = 0; kc < 4; ++kc)
        qf[kc] = *(const short8_t*)&Q[base + (size_t)(qg) * HD + kc * 32 + fk];

    {
        const float* cb = cosT + (size_t)qg * 64;
        const float* sb = sinT + (size_t)qg * 64;
#pragma unroll
        for (int kc = 0; kc < 2; ++kc) {
            float4 c0 = *(const float4*)&cb[kc * 32 + fk];
            float4 c1 = *(const float4*)&cb[kc * 32 + fk + 4];
            float4 s0 = *(const float4*)&sb[kc * 32 + fk];
            float4 s1 = *(const float4*)&sb[kc * 32 + fk + 4];
            float cv[8] = {c0.x, c0.y, c0.z, c0.w, c1.x, c1.y, c1.z, c1.w};
            float sv[8] = {s0.x, s0.y, s0.z, s0.w, s1.x, s1.y, s1.z, s1.w};
#pragma unroll
            for (int e = 0; e < 8; ++e) {
                float q1 = bf2f(qf[kc][e]), q2 = bf2f(qf[kc + 2][e]);
                qf[kc][e]     = f2bf((q1 * cv[e] - q2 * sv[e]) * SCALE_LOG2E);
                qf[kc + 2][e] = f2bf((q2 * cv[e] + q1 * sv[e]) * SCALE_LOG2E);
            }
        }
    }

    f32x4 acc[8];
#pragma unroll
    for (int dt = 0; dt < 8; ++dt) acc[dt] = (f32x4){0.f, 0.f, 0.f, 0.f};
    float m_r = -1e30f, l_r = 0.f;

    const int ktmax = qt * 2 + 1;

    short8_t kreg[2], vreg[2];
#pragma unroll
    for (int p = 0; p < 2; ++p) {
        kreg[p] = *(const short8_t*)&K[base + (size_t)(p * 32 + kr) * HD + kc8];
        vreg[p] = *(const short8_t*)&V[base + (size_t)(p * 64 + vd) * SEQ + vc8];
    }
#pragma unroll
    for (int p = 0; p < 2; ++p) {
        *(short8_t*)&Kl[(p * 32 + kr) * 136 + kc8] = kreg[p];
        *(short8_t*)&Vt[(p * 64 + vd) * 88 + vc8] = vreg[p];
    }
    __syncthreads();

    for (int kt = 0; kt <= ktmax; ++kt) {
        const bool active = (kt * 64 <= qbase + 15);
        f32x4 st[4];
        if (active) {
            __builtin_amdgcn_s_setprio(1);
#pragma unroll
            for (int nt = 0; nt < 4; ++nt) {
                f32x4 a = (f32x4){0.f, 0.f, 0.f, 0.f};
#pragma unroll
                for (int kc = 0; kc < 4; ++kc) {
                    short8_t kf = *(const short8_t*)&Kl[(nt * 16 + fr) * 136 + kc * 32 + fk];
                    a = __builtin_amdgcn_mfma_f32_16x16x32_bf16(kf, qf[kc], a, 0, 0, 0);
                }
                st[nt] = a;
            }
            __builtin_amdgcn_s_setprio(0);
        }

        if (kt < ktmax) {
            const size_t kb2 = base + (size_t)((kt + 1) * 64) * HD;
            const size_t vb2 = base + (size_t)(kt + 1) * 64;
#pragma unroll
            for (int p = 0; p < 2; ++p) {
                kreg[p] = *(const short8_t*)&K[kb2 + (size_t)(p * 32 + kr) * HD + kc8];
                vreg[p] = *(const short8_t*)&V[vb2 + (size_t)(p * 64 + vd) * SEQ + vc8];
            }
        }

        if (active) {
            const bool needMask = (kt * 64 + 63 > qbase);
            float rmax = -1e30f;
            if (needMask) {
#pragma unroll
                for (int nt = 0; nt < 4; ++nt)
#pragma unroll
                    for (int jj = 0; jj < 4; ++jj) {
                        int kg = kt * 64 + nt * 16 + fq + jj;
                        float sv = st[nt][jj];
                        sv = (kg > qg) ? -1e30f : sv;
                        st[nt][jj] = sv;
                        rmax = fmaxf(rmax, sv);
                    }
            } else {
#pragma unroll
                for (int nt = 0; nt < 4; ++nt)
#pragma unroll
                    for (int jj = 0; jj < 4; ++jj) rmax = fmaxf(rmax, st[nt][jj]);
            }
            rmax = fmaxf(rmax, __shfl_xor(rmax, 16));
            rmax = fmaxf(rmax, __shfl_xor(rmax, 32));

            // defer-max in log2 domain: 11.5 ≈ 8 * log2(e)
            const bool doRescale = !(m_r > -1e29f && __all(rmax - m_r <= 11.5f));
            float m_new = doRescale ? fmaxf(m_r, rmax) : m_r;
            float rsum = 0.f;
#pragma unroll
            for (int nt = 0; nt < 4; ++nt) {
                s16x4 pk;
#pragma unroll
                for (int jj = 0; jj < 4; ++jj) {
                    float p = exp2f(st[nt][jj] - m_new);
                    rsum += p;
                    pk[jj] = f2bf(p);
                }
                *(s16x4*)&Pl[w][fr * 88 + nt * 16 + fq] = pk;
            }
            rsum += __shfl_xor(rsum, 16);
            rsum += __shfl_xor(rsum, 32);
            if (doRescale) {
                float corr = exp2f(m_r - m_new);
                l_r = l_r * corr + rsum;
                m_r = m_new;
                float c4[4];
#pragma unroll
                for (int jj = 0; jj < 4; ++jj) c4[jj] = __shfl(corr, fq + jj);
#pragma unroll
                for (int dt = 0; dt < 8; ++dt)
#pragma unroll
                    for (int jj = 0; jj < 4; ++jj) acc[dt][jj] *= c4[jj];
            } else {
                l_r += rsum;
            }

            __builtin_amdgcn_s_setprio(1);
#pragma unroll
            for (int kc = 0; kc < 2; ++kc) {
                short8_t pf = *(const short8_t*)&Pl[w][fr * 88 + kc * 32 + fk];
#pragma unroll
                for (int dt = 0; dt < 8; ++dt) {
                    short8_t vf = *(const short8_t*)&Vt[(dt * 16 + fr) * 88 + kc * 32 + fk];
                    acc[dt] = __builtin_amdgcn_mfma_f32_16x16x32_bf16(pf, vf, acc[dt], 0, 0, 0);
                }
            }
            __builtin_amdgcn_s_setprio(0);
        }

        __syncthreads();
        if (kt < ktmax) {
#pragma unroll
            for (int p = 0; p < 2; ++p) {
                *(short8_t*)&Kl[(p * 32 + kr) * 136 + kc8] = kreg[p];
                *(short8_t*)&Vt[(p * 64 + vd) * 88 + vc8] = vreg[p];
            }
            __syncthreads();
        }
    }

    float linv[4];
#pragma unroll
    for (int jj = 0; jj < 4; ++jj) linv[jj] = 1.f / __shfl(l_r, fq + jj);
#pragma unroll
    for (int dt = 0; dt < 8; ++dt) {
#pragma unroll
        for (int jj = 0; jj < 4; ++jj) {
            int qrow = qbase + fq + jj;
            int d = dt * 16 + fr;
            AO[((size_t)(qrow * BATCH + b)) * DM + h * HD + d] = f2bf(acc[dt][jj] * linv[jj]);
        }
    }
}

extern "C" void kernel_launch(void* const* d_in, const int* in_sizes, int n_in,
                              void* d_out, int out_size, void* d_ws, size_t ws_size,
                              hipStream_t stream) {
    (void)in_sizes; (void)n_in; (void)out_size; (void)ws_size;
    const float* x  = (const float*)d_in[0];
    const float* nw = (const float*)d_in[3];
    const float* qw = (const float*)d_in[4];
    const float* qbias = (const float*)d_in[5];
    const float* kw = (const float*)d_in[6];
    const float* kbias = (const float*)d_in[7];
    const float* vw = (const float*)d_in[8];
    const float* vbias = (const float*)d_in[9];
    const float* ow = (const float*)d_in[10];
    const float* obias = (const float*)d_in[11];
    float* out = (float*)d_out;

    char* ws = (char*)d_ws;
    size_t off = 0;
    float* cosT = (float*)(ws + off); off += (size_t)SEQ * 64 * 4;
    float* sinT = (float*)(ws + off); off += (size_t)SEQ * 64 * 4;
    short* wqkv = (short*)(ws + off); off += (size_t)3 * DM * DM * 2;
    short* wo   = (short*)(ws + off); off += (size_t)DM * DM * 2;
    short* xn   = (short*)(ws + off); off += (size_t)SEQ * BATCH * DM * 2;  // reused as AO
    short* qd   = (short*)(ws + off); off += (size_t)SEQ * BATCH * DM * 2;
    short* kd   = (short*)(ws + off); off += (size_t)SEQ * BATCH * DM * 2;
    short* vd   = (short*)(ws + off); off += (size_t)SEQ * BATCH * DM * 2;
    short* ao   = xn;

    hipFuncSetAttribute((const void*)gemm_db<0>, hipFuncAttributeMaxDynamicSharedMemorySize, 65536);
    hipFuncSetAttribute((const void*)gemm_db<1>, hipFuncAttributeMaxDynamicSharedMemorySize, 65536);

    prep_kernel<<<2560 + SEQ * BATCH, 256, 0, stream>>>(qw, kw, vw, ow, wqkv, x, nw, xn, cosT, sinT);
    gemm_db<0><<<dim3(3 * DM / 128, SEQ * BATCH / 128), 256, 65536, stream>>>(
        xn, wqkv, 3 * DM, DM, qd, kd, vd, qbias, kbias, vbias, nullptr, nullptr);
    rope_k_kernel<<<BATCH * NH * SEQ / 4, 256, 0, stream>>>(kd, cosT, sinT);
    attn_kernel<<<dim3(SEQ / 128, BATCH * NH), 512, 0, stream>>>(qd, kd, vd, cosT, sinT, ao);
    gemm_db<1><<<dim3(DM / 128, SEQ * BATCH / 128), 256, 65536, stream>>>(
        ao, wo, DM, DM, nullptr, nullptr, nullptr, nullptr, nullptr, nullptr, out, obias);
}

// Round 9
// 253.412 us; speedup vs baseline: 1.6731x; 1.1074x over previous
//
#include <hip/hip_runtime.h>
#include <hip/hip_bf16.h>
#include <cstdint>

typedef __attribute__((ext_vector_type(8))) short short8_t;
typedef __attribute__((ext_vector_type(4))) short s16x4;
typedef __attribute__((ext_vector_type(4))) float f32x4;

#define SEQ 2048
#define BATCH 2
#define DM 2048
#define NH 16
#define HD 128
#define SCALE_LOG2E 0.1275174400948802f   // (1/sqrt(128)) * log2(e)

__device__ __forceinline__ short f2bf(float f) {
    union { __hip_bfloat16 h; short s; } u; u.h = __float2bfloat16(f); return u.s;
}
__device__ __forceinline__ float bf2f(short s) {
    union { short s; __hip_bfloat16 h; } u; u.s = s; return __bfloat162float(u.h);
}

#define DSREAD(d, a) asm volatile("ds_read_b128 %0, %1" : "=&v"(d) : "v"(a))

// ---------------- fused prep: weight cast + rope table + L2 norm ----------------
__global__ void __launch_bounds__(256) prep_kernel(const float* __restrict__ qw,
                                                   const float* __restrict__ kw,
                                                   const float* __restrict__ vw,
                                                   const float* __restrict__ ow,
                                                   short* __restrict__ wqkv,
                                                   const float* __restrict__ x,
                                                   const float* __restrict__ nw,
                                                   short* __restrict__ xn,
                                                   float* __restrict__ cosT,
                                                   float* __restrict__ sinT) {
    const int bid = blockIdx.x;
    const int t = threadIdx.x;
    if (bid < 2048) {
        const int per = DM * DM / 4;
        int i = bid * 256 + t;
        const int stride = 2048 * 256;
        for (; i < 4 * per; i += stride) {
            int region = i / per;
            int off = i - region * per;
            const float* src = region == 0 ? qw : (region == 1 ? kw : (region == 2 ? vw : ow));
            float4 v = ((const float4*)src)[off];
            s16x4 o;
            o[0] = f2bf(v.x); o[1] = f2bf(v.y); o[2] = f2bf(v.z); o[3] = f2bf(v.w);
            ((s16x4*)(wqkv + (size_t)region * DM * DM))[off] = o;
        }
    } else if (bid < 2560) {
        int j = (bid - 2048) * 256 + t;
        int tpos = j >> 6, i = j & 63;
        float inv = exp2f(-(2.0f * (float)i / 128.0f) * log2f(10000.0f));
        float a = (float)tpos * inv;
        cosT[tpos * 64 + i] = cosf(a);
        sinT[tpos * 64 + i] = sinf(a);
    } else {
        __shared__ float red[4];
        int row = bid - 2560;
        const float* xr = x + (size_t)row * DM;
        short* outr = xn + (size_t)row * DM;
        float vals[8];
        float ss = 0.f;
#pragma unroll
        for (int i = 0; i < 8; ++i) { float v = xr[t + 256 * i]; vals[i] = v; ss += v * v; }
#pragma unroll
        for (int off = 1; off < 64; off <<= 1) ss += __shfl_xor(ss, off);
        int lane = t & 63, wv = t >> 6;
        if (lane == 0) red[wv] = ss;
        __syncthreads();
        float tot = red[0] + red[1] + red[2] + red[3];
        float inv = 1.f / (sqrtf(tot) + 1e-5f);
#pragma unroll
        for (int i = 0; i < 8; ++i)
            outr[t + 256 * i] = f2bf(vals[i] * inv * nw[t + 256 * i]);
    }
}

// ========== 128x128 BK=64 GEMM, double-buffered, counted vmcnt, asm ds_read ==========
template <int MODE>
__global__ void __launch_bounds__(256) gemm_db(const short* __restrict__ A,
                                               const short* __restrict__ B,
                                               int N, int K,
                                               short* __restrict__ oq, short* __restrict__ ok,
                                               short* __restrict__ ov,
                                               const float* __restrict__ bq,
                                               const float* __restrict__ bk,
                                               const float* __restrict__ bv,
                                               float* __restrict__ outF,
                                               const float* __restrict__ bias) {
    extern __shared__ short lds[];
    const int tid = threadIdx.x;
    const int lane = tid & 63;
    const int w = tid >> 6;
    const int wr = w >> 1, wc = w & 1;
    const int brow = blockIdx.y * 128;
    const int bcol = blockIdx.x * 128;

    const short* gA[4]; const short* gB[4]; int ldsC[4];
#pragma unroll
    for (int p = 0; p < 4; ++p) {
        int c = p * 256 + tid;
        int row = c >> 3;
        int slot = (c & 7) ^ (row & 7);
        gA[p] = A + (size_t)(brow + row) * K + slot * 8;
        gB[p] = B + (size_t)(bcol + row) * K + slot * 8;
        ldsC[p] = c * 8;
    }
    const uint32_t ldsBase = (uint32_t)(uintptr_t)&lds[0];

    f32x4 acc[4][4];
#pragma unroll
    for (int i = 0; i < 4; ++i)
#pragma unroll
        for (int j = 0; j < 4; ++j) acc[i][j] = (f32x4){0.f, 0.f, 0.f, 0.f};

    const int fr = lane & 15;
    const int fs = lane >> 4;
    uint32_t aOff[4][2], bOff[4][2];
#pragma unroll
    for (int i = 0; i < 4; ++i)
#pragma unroll
        for (int ks = 0; ks < 2; ++ks) {
            int ch = (ks * 4 + fs) ^ (fr & 7);
            int ar = wr * 64 + i * 16 + fr;
            int br = wc * 64 + i * 16 + fr;
            aOff[i][ks] = ldsBase + (uint32_t)(ar * 128 + ch * 16);
            bOff[i][ks] = ldsBase + 32768u + (uint32_t)(br * 128 + ch * 16);
        }

    const int nt = K >> 6;
#pragma unroll
    for (int p = 0; p < 4; ++p)
        __builtin_amdgcn_global_load_lds((const __attribute__((address_space(1))) void*)gA[p],
                                         (__attribute__((address_space(3))) void*)(lds + ldsC[p]), 16, 0, 0);
#pragma unroll
    for (int p = 0; p < 4; ++p)
        __builtin_amdgcn_global_load_lds((const __attribute__((address_space(1))) void*)gB[p],
                                         (__attribute__((address_space(3))) void*)(lds + 16384 + ldsC[p]), 16, 0, 0);

    for (int t = 0; t < nt; ++t) {
        const int cur = t & 1;
        if (t + 1 < nt) {
            const int nb = (t + 1) & 1;
            const int kb = (t + 1) << 6;
#pragma unroll
            for (int p = 0; p < 4; ++p)
                __builtin_amdgcn_global_load_lds((const __attribute__((address_space(1))) void*)(gA[p] + kb),
                                                 (__attribute__((address_space(3))) void*)(lds + nb * 8192 + ldsC[p]), 16, 0, 0);
#pragma unroll
            for (int p = 0; p < 4; ++p)
                __builtin_amdgcn_global_load_lds((const __attribute__((address_space(1))) void*)(gB[p] + kb),
                                                 (__attribute__((address_space(3))) void*)(lds + 16384 + nb * 8192 + ldsC[p]), 16, 0, 0);
            asm volatile("s_waitcnt vmcnt(8)" ::: "memory");
        } else {
            asm volatile("s_waitcnt vmcnt(0)" ::: "memory");
        }
        __builtin_amdgcn_s_barrier();

        const uint32_t ab = (uint32_t)(cur * 16384);
        short8_t af[4][2], bfv[4][2];
#pragma unroll
        for (int i = 0; i < 4; ++i)
#pragma unroll
            for (int ks = 0; ks < 2; ++ks) DSREAD(af[i][ks], aOff[i][ks] + ab);
#pragma unroll
        for (int j = 0; j < 4; ++j)
#pragma unroll
            for (int ks = 0; ks < 2; ++ks) DSREAD(bfv[j][ks], bOff[j][ks] + ab);
        asm volatile("s_waitcnt lgkmcnt(0)" ::: "memory");
        __builtin_amdgcn_sched_barrier(0);

        __builtin_amdgcn_s_setprio(1);
#pragma unroll
        for (int ks = 0; ks < 2; ++ks)
#pragma unroll
            for (int i = 0; i < 4; ++i)
#pragma unroll
                for (int j = 0; j < 4; ++j)
                    acc[i][j] = __builtin_amdgcn_mfma_f32_16x16x32_bf16(af[i][ks], bfv[j][ks], acc[i][j], 0, 0, 0);
        __builtin_amdgcn_s_setprio(0);
        __builtin_amdgcn_s_barrier();
    }

    const int fq = (lane >> 4) * 4;
#pragma unroll
    for (int i = 0; i < 4; ++i) {
        int mrow = brow + wr * 64 + i * 16 + fq;
#pragma unroll
        for (int j = 0; j < 4; ++j) {
            int ncol = bcol + wc * 64 + j * 16 + fr;
            if (MODE == 0) {
                int which = ncol >> 11;
                int hl = ncol & 2047;
                int h = hl >> 7, d = hl & 127;
                const float* bp = which == 0 ? bq : (which == 1 ? bk : bv);
                short* dst = which == 0 ? oq : (which == 1 ? ok : ov);
                float bval = bp[hl];
#pragma unroll
                for (int jj = 0; jj < 4; ++jj) {
                    int m = mrow + jj;
                    int s = m >> 1, b = m & 1;
                    float v = acc[i][j][jj] + bval;
                    size_t idx;
                    if (which == 2)
                        idx = (((size_t)(b * NH + h)) * HD + d) * SEQ + s;   // V transposed (b,h,d,s)
                    else
                        idx = (((size_t)(b * NH + h)) * SEQ + s) * HD + d;   // (b,h,s,d)
                    dst[idx] = f2bf(v);
                }
            } else {
                float bval = bias[ncol];
#pragma unroll
                for (int jj = 0; jj < 4; ++jj) {
                    int m = mrow + jj;
                    outF[(size_t)m * N + ncol] = acc[i][j][jj] + bval;
                }
            }
        }
    }
}

// ---------------- RoPE in-place on k only (b,h,s,d) bf16 ----------------
__global__ void __launch_bounds__(256) rope_k_kernel(short* __restrict__ k,
                                                     const float* __restrict__ cosT,
                                                     const float* __restrict__ sinT) {
    int w = threadIdx.x >> 6, lane = threadIdx.x & 63;
    int idx = blockIdx.x * 4 + w;
    int s = idx & (SEQ - 1);
    size_t base = (size_t)idx * HD;
    float c = cosT[s * 64 + lane], sn = sinT[s * 64 + lane];
    float k1 = bf2f(k[base + lane]), k2 = bf2f(k[base + lane + 64]);
    k[base + lane] = f2bf(k1 * c - k2 * sn);
    k[base + lane + 64] = f2bf(k2 * c + k1 * sn);
}

// ---------------- Flash attention (causal), 8 waves x 16 q-rows (QBLK=128), KV tile 64 ----
// Grid (bh, ym): qt = ym<8 ? 2*ym : 15-2*(ym-8)  -> co-resident pairs (2a, 15-2a)
// have constant total work (load balance). exp2-domain softmax; async-STAGE; defer-max.
__global__ void __launch_bounds__(512) attn_kernel(const short* __restrict__ Q,
                                                   const short* __restrict__ K,
                                                   const short* __restrict__ V,
                                                   const float* __restrict__ cosT,
                                                   const float* __restrict__ sinT,
                                                   short* __restrict__ AO) {
    __shared__ short Kl[64 * 136];
    __shared__ short Vt[128 * 88];
    __shared__ short Pl[8][16 * 88];

    const int bh = blockIdx.x;
    const int ym = blockIdx.y;
    const int qt = (ym < 8) ? (2 * ym) : (15 - 2 * (ym - 8));
    const int b = bh >> 4;
    const int h = bh & 15;
    const size_t base = (size_t)bh * (SEQ * HD);
    const int tid = threadIdx.x;
    const int lane = tid & 63;
    const int w = tid >> 6;
    const int fr = lane & 15;
    const int fk = (lane >> 4) * 8;
    const int fq = (lane >> 4) * 4;
    const int qbase = qt * 128 + w * 16;
    const int qg = qbase + fr;

    const int kr = tid >> 4;
    const int kc8 = (tid & 15) * 8;
    const int vd = tid >> 3;
    const int vc8 = (tid & 7) * 8;

    short8_t qf[4];
#pragma unroll
    for (int kc = 0; kc < 4; ++kc)
        qf[kc] = *(const short8_t*)&Q[base + (size_t)(qg) * HD + kc * 32 + fk];

    {
        const float* cb = cosT + (size_t)qg * 64;
        const float* sb = sinT + (size_t)qg * 64;
#pragma unroll
        for (int kc = 0; kc < 2; ++kc) {
            float4 c0 = *(const float4*)&cb[kc * 32 + fk];
            float4 c1 = *(const float4*)&cb[kc * 32 + fk + 4];
            float4 s0 = *(const float4*)&sb[kc * 32 + fk];
            float4 s1 = *(const float4*)&sb[kc * 32 + fk + 4];
            float cv[8] = {c0.x, c0.y, c0.z, c0.w, c1.x, c1.y, c1.z, c1.w};
            float sv[8] = {s0.x, s0.y, s0.z, s0.w, s1.x, s1.y, s1.z, s1.w};
#pragma unroll
            for (int e = 0; e < 8; ++e) {
                float q1 = bf2f(qf[kc][e]), q2 = bf2f(qf[kc + 2][e]);
                qf[kc][e]     = f2bf((q1 * cv[e] - q2 * sv[e]) * SCALE_LOG2E);
                qf[kc + 2][e] = f2bf((q2 * cv[e] + q1 * sv[e]) * SCALE_LOG2E);
            }
        }
    }

    f32x4 acc[8];
#pragma unroll
    for (int dt = 0; dt < 8; ++dt) acc[dt] = (f32x4){0.f, 0.f, 0.f, 0.f};
    float m_r = -1e30f, l_r = 0.f;

    const int ktmax = qt * 2 + 1;

    short8_t kreg[2], vreg[2];
#pragma unroll
    for (int p = 0; p < 2; ++p) {
        kreg[p] = *(const short8_t*)&K[base + (size_t)(p * 32 + kr) * HD + kc8];
        vreg[p] = *(const short8_t*)&V[base + (size_t)(p * 64 + vd) * SEQ + vc8];
    }
#pragma unroll
    for (int p = 0; p < 2; ++p) {
        *(short8_t*)&Kl[(p * 32 + kr) * 136 + kc8] = kreg[p];
        *(short8_t*)&Vt[(p * 64 + vd) * 88 + vc8] = vreg[p];
    }
    __syncthreads();

    for (int kt = 0; kt <= ktmax; ++kt) {
        const bool active = (kt * 64 <= qbase + 15);
        f32x4 st[4];
        if (active) {
            __builtin_amdgcn_s_setprio(1);
#pragma unroll
            for (int nt = 0; nt < 4; ++nt) {
                f32x4 a = (f32x4){0.f, 0.f, 0.f, 0.f};
#pragma unroll
                for (int kc = 0; kc < 4; ++kc) {
                    short8_t kf = *(const short8_t*)&Kl[(nt * 16 + fr) * 136 + kc * 32 + fk];
                    a = __builtin_amdgcn_mfma_f32_16x16x32_bf16(kf, qf[kc], a, 0, 0, 0);
                }
                st[nt] = a;
            }
            __builtin_amdgcn_s_setprio(0);
        }

        if (kt < ktmax) {
            const size_t kb2 = base + (size_t)((kt + 1) * 64) * HD;
            const size_t vb2 = base + (size_t)(kt + 1) * 64;
#pragma unroll
            for (int p = 0; p < 2; ++p) {
                kreg[p] = *(const short8_t*)&K[kb2 + (size_t)(p * 32 + kr) * HD + kc8];
                vreg[p] = *(const short8_t*)&V[vb2 + (size_t)(p * 64 + vd) * SEQ + vc8];
            }
        }

        if (active) {
            const bool needMask = (kt * 64 + 63 > qbase);
            float rmax = -1e30f;
            if (needMask) {
#pragma unroll
                for (int nt = 0; nt < 4; ++nt)
#pragma unroll
                    for (int jj = 0; jj < 4; ++jj) {
                        int kg = kt * 64 + nt * 16 + fq + jj;
                        float sv = st[nt][jj];
                        sv = (kg > qg) ? -1e30f : sv;
                        st[nt][jj] = sv;
                        rmax = fmaxf(rmax, sv);
                    }
            } else {
#pragma unroll
                for (int nt = 0; nt < 4; ++nt)
#pragma unroll
                    for (int jj = 0; jj < 4; ++jj) rmax = fmaxf(rmax, st[nt][jj]);
            }
            rmax = fmaxf(rmax, __shfl_xor(rmax, 16));
            rmax = fmaxf(rmax, __shfl_xor(rmax, 32));

            const bool doRescale = !(m_r > -1e29f && __all(rmax - m_r <= 11.5f));
            float m_new = doRescale ? fmaxf(m_r, rmax) : m_r;
            float rsum = 0.f;
#pragma unroll
            for (int nt = 0; nt < 4; ++nt) {
                s16x4 pk;
#pragma unroll
                for (int jj = 0; jj < 4; ++jj) {
                    float p = exp2f(st[nt][jj] - m_new);
                    rsum += p;
                    pk[jj] = f2bf(p);
                }
                *(s16x4*)&Pl[w][fr * 88 + nt * 16 + fq] = pk;
            }
            rsum += __shfl_xor(rsum, 16);
            rsum += __shfl_xor(rsum, 32);
            if (doRescale) {
                float corr = exp2f(m_r - m_new);
                l_r = l_r * corr + rsum;
                m_r = m_new;
                float c4[4];
#pragma unroll
                for (int jj = 0; jj < 4; ++jj) c4[jj] = __shfl(corr, fq + jj);
#pragma unroll
                for (int dt = 0; dt < 8; ++dt)
#pragma unroll
                    for (int jj = 0; jj < 4; ++jj) acc[dt][jj] *= c4[jj];
            } else {
                l_r += rsum;
            }

            __builtin_amdgcn_s_setprio(1);
#pragma unroll
            for (int kc = 0; kc < 2; ++kc) {
                short8_t pf = *(const short8_t*)&Pl[w][fr * 88 + kc * 32 + fk];
#pragma unroll
                for (int dt = 0; dt < 8; ++dt) {
                    short8_t vf = *(const short8_t*)&Vt[(dt * 16 + fr) * 88 + kc * 32 + fk];
                    acc[dt] = __builtin_amdgcn_mfma_f32_16x16x32_bf16(pf, vf, acc[dt], 0, 0, 0);
                }
            }
            __builtin_amdgcn_s_setprio(0);
        }

        __syncthreads();
        if (kt < ktmax) {
#pragma unroll
            for (int p = 0; p < 2; ++p) {
                *(short8_t*)&Kl[(p * 32 + kr) * 136 + kc8] = kreg[p];
                *(short8_t*)&Vt[(p * 64 + vd) * 88 + vc8] = vreg[p];
            }
            __syncthreads();
        }
    }

    float linv[4];
#pragma unroll
    for (int jj = 0; jj < 4; ++jj) linv[jj] = 1.f / __shfl(l_r, fq + jj);
#pragma unroll
    for (int dt = 0; dt < 8; ++dt) {
#pragma unroll
        for (int jj = 0; jj < 4; ++jj) {
            int qrow = qbase + fq + jj;
            int d = dt * 16 + fr;
            AO[((size_t)(qrow * BATCH + b)) * DM + h * HD + d] = f2bf(acc[dt][jj] * linv[jj]);
        }
    }
}

extern "C" void kernel_launch(void* const* d_in, const int* in_sizes, int n_in,
                              void* d_out, int out_size, void* d_ws, size_t ws_size,
                              hipStream_t stream) {
    (void)in_sizes; (void)n_in; (void)out_size; (void)ws_size;
    const float* x  = (const float*)d_in[0];
    const float* nw = (const float*)d_in[3];
    const float* qw = (const float*)d_in[4];
    const float* qbias = (const float*)d_in[5];
    const float* kw = (const float*)d_in[6];
    const float* kbias = (const float*)d_in[7];
    const float* vw = (const float*)d_in[8];
    const float* vbias = (const float*)d_in[9];
    const float* ow = (const float*)d_in[10];
    const float* obias = (const float*)d_in[11];
    float* out = (float*)d_out;

    char* ws = (char*)d_ws;
    size_t off = 0;
    float* cosT = (float*)(ws + off); off += (size_t)SEQ * 64 * 4;
    float* sinT = (float*)(ws + off); off += (size_t)SEQ * 64 * 4;
    short* wqkv = (short*)(ws + off); off += (size_t)3 * DM * DM * 2;
    short* wo   = (short*)(ws + off); off += (size_t)DM * DM * 2;
    short* xn   = (short*)(ws + off); off += (size_t)SEQ * BATCH * DM * 2;  // reused as AO
    short* qd   = (short*)(ws + off); off += (size_t)SEQ * BATCH * DM * 2;
    short* kd   = (short*)(ws + off); off += (size_t)SEQ * BATCH * DM * 2;
    short* vd   = (short*)(ws + off); off += (size_t)SEQ * BATCH * DM * 2;
    short* ao   = xn;

    hipFuncSetAttribute((const void*)gemm_db<0>, hipFuncAttributeMaxDynamicSharedMemorySize, 65536);
    hipFuncSetAttribute((const void*)gemm_db<1>, hipFuncAttributeMaxDynamicSharedMemorySize, 65536);

    prep_kernel<<<2560 + SEQ * BATCH, 256, 0, stream>>>(qw, kw, vw, ow, wqkv, x, nw, xn, cosT, sinT);
    gemm_db<0><<<dim3(3 * DM / 128, SEQ * BATCH / 128), 256, 65536, stream>>>(
        xn, wqkv, 3 * DM, DM, qd, kd, vd, qbias, kbias, vbias, nullptr, nullptr);
    rope_k_kernel<<<BATCH * NH * SEQ / 4, 256, 0, stream>>>(kd, cosT, sinT);
    attn_kernel<<<dim3(BATCH * NH, SEQ / 128), 512, 0, stream>>>(qd, kd, vd, cosT, sinT, ao);
    gemm_db<1><<<dim3(DM / 128, SEQ * BATCH / 128), 256, 65536, stream>>>(
        ao, wo, DM, DM, nullptr, nullptr, nullptr, nullptr, nullptr, nullptr, out, obias);
}